// Round 3
// baseline (195.395 us; speedup 1.0000x reference)
//
#include <hip/hip_runtime.h>

typedef unsigned short u16;
typedef unsigned int u32;
typedef __attribute__((ext_vector_type(8))) short bf16x8;
typedef __attribute__((ext_vector_type(4))) float f32x4;

#define NTOK 4096

__device__ __forceinline__ float b2f(u16 u) {
    u32 v = ((u32)u) << 16;
    return __builtin_bit_cast(float, v);
}
__device__ __forceinline__ u16 f2b(float f) {
    u32 u = __builtin_bit_cast(u32, f);
    u32 r = (u + 0x7fffu + ((u >> 16) & 1u)) >> 16;  // RNE
    return (u16)r;
}
__device__ __forceinline__ u32 pack2(float lo, float hi) {
    return (u32)f2b(lo) | ((u32)f2b(hi) << 16);
}
__device__ __forceinline__ bf16x8 cvt8(const float* __restrict__ p) {
    float4 a = *(const float4*)p;
    float4 b = *(const float4*)(p + 4);
    bf16x8 r;
    r[0] = (short)f2b(a.x); r[1] = (short)f2b(a.y);
    r[2] = (short)f2b(a.z); r[3] = (short)f2b(a.w);
    r[4] = (short)f2b(b.x); r[5] = (short)f2b(b.y);
    r[6] = (short)f2b(b.z); r[7] = (short)f2b(b.w);
    return r;
}
__device__ __forceinline__ bf16x8 cat4(short4 a, short4 b) {
    bf16x8 r;
    r[0] = a.x; r[1] = a.y; r[2] = a.z; r[3] = a.w;
    r[4] = b.x; r[5] = b.y; r[6] = b.z; r[7] = b.w;
    return r;
}

// ---------------------------------------------------------------------------
// Kernel 1: QKV projection. grid (64,4) blocks of 512 threads (8 waves).
// Waves 0-3: Q,K GEMMs for token group (wv&3); waves 4-7: V GEMM + stores.
// ---------------------------------------------------------------------------
__global__ __launch_bounds__(512) void qkv_kernel(
    const float* __restrict__ seg, const float* __restrict__ gau,
    const float* __restrict__ Wq, const float* __restrict__ bq,
    const float* __restrict__ Wk, const float* __restrict__ bk,
    const float* __restrict__ Wv, const float* __restrict__ bv,
    u16* __restrict__ Qt, u16* __restrict__ Kt,
    u16* __restrict__ Vtok, u16* __restrict__ Vchan)
{
    __shared__ __align__(16) u16 sSegT[64 * 64];
    __shared__ __align__(16) u16 sGauT[64 * 64];
    const int tid = threadIdx.x;
    const int b = blockIdx.y;
    const int n0 = blockIdx.x * 64;

    // load [c][n] coalesced fp32, store transposed [tok][c] bf16, XOR swizzle
    for (int idx = tid; idx < 4096; idx += 512) {
        int c = idx >> 6, t = idx & 63;
        int sw = t * 64 + ((((c >> 3) ^ (t & 7)) << 3) | (c & 7));
        sSegT[sw] = f2b(seg[(size_t)(b * 64 + c) * NTOK + n0 + t]);
        sGauT[sw] = f2b(gau[(size_t)(b * 64 + c) * NTOK + n0 + t]);
    }
    __syncthreads();

    const int lane = tid & 63;
    const int wv = tid >> 6;          // 0..7
    const int tb = wv & 3;            // token group
    const int task = wv >> 2;         // 0: Q,K   1: V
    const int q = lane & 15, g = lane >> 4;
    const int tok = tb * 16 + q;

    const size_t obase = (size_t)b * NTOK * 64;
    const size_t rowb = (size_t)(n0 + tb * 16 + g * 4);

    if (task == 0) {
        bf16x8 as[2];
#pragma unroll
        for (int ks = 0; ks < 2; ++ks) {
            int c0 = ks * 32 + g * 8;
            int sw = tok * 64 + (((c0 >> 3) ^ (tok & 7)) << 3);
            as[ks] = *(const bf16x8*)&sSegT[sw];
        }
#pragma unroll
        for (int ob = 0; ob < 4; ++ob) {
            int o = ob * 16 + q;
            {
                float bias = bq[o];
                f32x4 acc = {bias, bias, bias, bias};
                bf16x8 w0 = cvt8(&Wq[o * 64 + g * 8]);
                bf16x8 w1 = cvt8(&Wq[o * 64 + 32 + g * 8]);
                acc = __builtin_amdgcn_mfma_f32_16x16x32_bf16(as[0], w0, acc, 0, 0, 0);
                acc = __builtin_amdgcn_mfma_f32_16x16x32_bf16(as[1], w1, acc, 0, 0, 0);
#pragma unroll
                for (int j = 0; j < 4; ++j)
                    Qt[obase + (rowb + j) * 64 + o] = f2b(acc[j]);
            }
            {
                float bias = bk[o];
                f32x4 acc = {bias, bias, bias, bias};
                bf16x8 w0 = cvt8(&Wk[o * 64 + g * 8]);
                bf16x8 w1 = cvt8(&Wk[o * 64 + 32 + g * 8]);
                acc = __builtin_amdgcn_mfma_f32_16x16x32_bf16(as[0], w0, acc, 0, 0, 0);
                acc = __builtin_amdgcn_mfma_f32_16x16x32_bf16(as[1], w1, acc, 0, 0, 0);
#pragma unroll
                for (int j = 0; j < 4; ++j)
                    Kt[obase + (rowb + j) * 64 + o] = f2b(acc[j]);
            }
        }
    } else {
        bf16x8 ag[2];
#pragma unroll
        for (int ks = 0; ks < 2; ++ks) {
            int c0 = ks * 32 + g * 8;
            int sw = tok * 64 + (((c0 >> 3) ^ (tok & 7)) << 3);
            ag[ks] = *(const bf16x8*)&sGauT[sw];
        }
#pragma unroll
        for (int ob = 0; ob < 4; ++ob) {
            int o = ob * 16 + q;
            float bias = bv[o];
            f32x4 acc = {bias, bias, bias, bias};
            bf16x8 w0 = cvt8(&Wv[o * 64 + g * 8]);
            bf16x8 w1 = cvt8(&Wv[o * 64 + 32 + g * 8]);
            acc = __builtin_amdgcn_mfma_f32_16x16x32_bf16(ag[0], w0, acc, 0, 0, 0);
            acc = __builtin_amdgcn_mfma_f32_16x16x32_bf16(ag[1], w1, acc, 0, 0, 0);
            ushort4 v4;
            v4.x = f2b(acc[0]); v4.y = f2b(acc[1]);
            v4.z = f2b(acc[2]); v4.w = f2b(acc[3]);
#pragma unroll
            for (int j = 0; j < 4; ++j)
                Vtok[obase + (rowb + j) * 64 + o] = f2b(acc[j]);
            *(ushort4*)&Vchan[(size_t)(b * 64 + o) * NTOK + n0 + tb * 16 + g * 4] = v4;
        }
    }
}

// ---------------------------------------------------------------------------
// Kernel 2: flash attention (in-block K-split x4) + LN1 + FFN + LN2.
// grid (256,4), 256 threads = 4 waves. All 4 waves share the SAME 16 queries;
// wave wv owns keys [wv*1024, wv*1024+1024). Hot loop has NO LDS traffic:
// P stays in registers via a permuted-k MFMA (V A-frag loaded with the same
// key permutation P naturally has). Partials combined in LDS; wave 0 runs
// the fused epilogue.
// ---------------------------------------------------------------------------
__global__ __launch_bounds__(256, 4) void attn_kernel(
    const u16* __restrict__ Qt, const u16* __restrict__ Kt,
    const u16* __restrict__ Vtok, const u16* __restrict__ Vchan,
    const float* __restrict__ ln1w, const float* __restrict__ ln1b,
    const float* __restrict__ ln2w, const float* __restrict__ ln2b,
    const float* __restrict__ W1, const float* __restrict__ b1,
    const float* __restrict__ W2, const float* __restrict__ b2,
    float* __restrict__ out)
{
    __shared__ __align__(16) float sAcc[4][16][68];  // [wv][q][ch], pad 68
    __shared__ float sM[4][16], sL[4][16];
    __shared__ __align__(16) u16 sX[16 * 64];        // wave-0 FFN roundtrip

    const int tid = threadIdx.x;
    const int wv = tid >> 6;
    const int lane = tid & 63;
    const int q = lane & 15, g = lane >> 4;
    const int b = blockIdx.y;
    const int q0 = blockIdx.x * 16;
    const int n_q = q0 + q;
    const size_t tb_ = (size_t)b * NTOK * 64;

    // Q fragments (B-operand: col = query, k = channel)
    bf16x8 qf0 = *(const bf16x8*)&Qt[tb_ + (size_t)n_q * 64 + g * 8];
    bf16x8 qf1 = *(const bf16x8*)&Qt[tb_ + (size_t)n_q * 64 + 32 + g * 8];

    f32x4 zero4 = {0.f, 0.f, 0.f, 0.f};
    f32x4 acc[4];
#pragma unroll
    for (int i = 0; i < 4; ++i) acc[i] = zero4;
    float m = -1e30f, l = 0.f;

    const int kbeg = wv * 1024;
    const u16* Kp = &Kt[tb_ + (size_t)kbeg * 64];
    // V row pointers: channel cb*16+q, key offset g*4 (permuted-k A-frag)
    const u16* Vr0 = &Vchan[(size_t)(b * 64 + 0 * 16 + q) * NTOK + kbeg + g * 4];
    const u16* Vr1 = &Vchan[(size_t)(b * 64 + 1 * 16 + q) * NTOK + kbeg + g * 4];
    const u16* Vr2 = &Vchan[(size_t)(b * 64 + 2 * 16 + q) * NTOK + kbeg + g * 4];
    const u16* Vr3 = &Vchan[(size_t)(b * 64 + 3 * 16 + q) * NTOK + kbeg + g * 4];

    for (int kk = 0; kk < 1024; kk += 32) {
        bf16x8 kf00 = *(const bf16x8*)&Kp[q * 64 + g * 8];
        bf16x8 kf01 = *(const bf16x8*)&Kp[q * 64 + 32 + g * 8];
        bf16x8 kf10 = *(const bf16x8*)&Kp[(16 + q) * 64 + g * 8];
        bf16x8 kf11 = *(const bf16x8*)&Kp[(16 + q) * 64 + 32 + g * 8];
        Kp += 32 * 64;

        // V fragments, two b64 halves per channel block (keys kk+g*4.., kk+16+g*4..)
        short4 vl0 = *(const short4*)&Vr0[kk];
        short4 vh0 = *(const short4*)&Vr0[kk + 16];
        short4 vl1 = *(const short4*)&Vr1[kk];
        short4 vh1 = *(const short4*)&Vr1[kk + 16];
        short4 vl2 = *(const short4*)&Vr2[kk];
        short4 vh2 = *(const short4*)&Vr2[kk + 16];
        short4 vl3 = *(const short4*)&Vr3[kk];
        short4 vh3 = *(const short4*)&Vr3[kk + 16];

        f32x4 s0 = __builtin_amdgcn_mfma_f32_16x16x32_bf16(kf00, qf0, zero4, 0, 0, 0);
        s0 = __builtin_amdgcn_mfma_f32_16x16x32_bf16(kf01, qf1, s0, 0, 0, 0);
        f32x4 s1 = __builtin_amdgcn_mfma_f32_16x16x32_bf16(kf10, qf0, zero4, 0, 0, 0);
        s1 = __builtin_amdgcn_mfma_f32_16x16x32_bf16(kf11, qf1, s1, 0, 0, 0);

        // lane holds S[q][kbeg+kk + g*4+j] (s0) and [... +16+g*4+j] (s1)
        float sv[8];
#pragma unroll
        for (int j = 0; j < 4; ++j) { sv[j] = s0[j] * 0.125f; sv[4 + j] = s1[j] * 0.125f; }

        float tm = sv[0];
#pragma unroll
        for (int j = 1; j < 8; ++j) tm = fmaxf(tm, sv[j]);
        tm = fmaxf(tm, __shfl_xor(tm, 16));
        tm = fmaxf(tm, __shfl_xor(tm, 32));

        float mn = fmaxf(m, tm);
        float corr = __expf(m - mn);
        m = mn;

        float p[8];
        float ps = 0.f;
#pragma unroll
        for (int j = 0; j < 8; ++j) { p[j] = __expf(sv[j] - mn); ps += p[j]; }
        ps += __shfl_xor(ps, 16);
        ps += __shfl_xor(ps, 32);
        l = l * corr + ps;
#pragma unroll
        for (int i = 0; i < 4; ++i) acc[i] *= corr;

        // P packed in-register as the PV B-operand (same permuted key map)
        u32 pw0 = pack2(p[0], p[1]), pw1 = pack2(p[2], p[3]);
        u32 pw2 = pack2(p[4], p[5]), pw3 = pack2(p[6], p[7]);
        u32 pwv[4] = {pw0, pw1, pw2, pw3};
        bf16x8 pf = __builtin_bit_cast(bf16x8, *(const bf16x8*)pwv);

        acc[0] = __builtin_amdgcn_mfma_f32_16x16x32_bf16(cat4(vl0, vh0), pf, acc[0], 0, 0, 0);
        acc[1] = __builtin_amdgcn_mfma_f32_16x16x32_bf16(cat4(vl1, vh1), pf, acc[1], 0, 0, 0);
        acc[2] = __builtin_amdgcn_mfma_f32_16x16x32_bf16(cat4(vl2, vh2), pf, acc[2], 0, 0, 0);
        acc[3] = __builtin_amdgcn_mfma_f32_16x16x32_bf16(cat4(vl3, vh3), pf, acc[3], 0, 0, 0);
    }

    // ---- write per-wave partials, combine in wave 0 ----
    sM[wv][q] = m;
    sL[wv][q] = l;
#pragma unroll
    for (int cb = 0; cb < 4; ++cb)
        *(f32x4*)&sAcc[wv][q][cb * 16 + g * 4] = acc[cb];
    __syncthreads();
    if (wv != 0) return;

    float m0 = sM[0][q], m1 = sM[1][q], m2 = sM[2][q], m3 = sM[3][q];
    float M = fmaxf(fmaxf(m0, m1), fmaxf(m2, m3));
    float c0 = __expf(m0 - M), c1 = __expf(m1 - M);
    float c2 = __expf(m2 - M), c3 = __expf(m3 - M);
    float L = c0 * sL[0][q] + c1 * sL[1][q] + c2 * sL[2][q] + c3 * sL[3][q];

    f32x4 o[4];
#pragma unroll
    for (int cb = 0; cb < 4; ++cb) {
        f32x4 a0 = *(const f32x4*)&sAcc[0][q][cb * 16 + g * 4];
        f32x4 a1 = *(const f32x4*)&sAcc[1][q][cb * 16 + g * 4];
        f32x4 a2 = *(const f32x4*)&sAcc[2][q][cb * 16 + g * 4];
        f32x4 a3 = *(const f32x4*)&sAcc[3][q][cb * 16 + g * 4];
#pragma unroll
        for (int j = 0; j < 4; ++j)
            o[cb][j] = c0 * a0[j] + c1 * a1[j] + c2 * a2[j] + c3 * a3[j];
    }

    // ---- epilogue: lane owns channels cb*16 + g*4 + j of query n_q ----
    float inv_l = 1.0f / L;
    float x1[4][4];
#pragma unroll
    for (int cb = 0; cb < 4; ++cb) {
        ushort4 vv = *(const ushort4*)&Vtok[tb_ + (size_t)n_q * 64 + cb * 16 + g * 4];
        x1[cb][0] = o[cb][0] * inv_l + b2f(vv.x);
        x1[cb][1] = o[cb][1] * inv_l + b2f(vv.y);
        x1[cb][2] = o[cb][2] * inv_l + b2f(vv.z);
        x1[cb][3] = o[cb][3] * inv_l + b2f(vv.w);
    }

    // LN1
    float s_ = 0.f;
#pragma unroll
    for (int cb = 0; cb < 4; ++cb)
        for (int j = 0; j < 4; ++j) s_ += x1[cb][j];
    s_ += __shfl_xor(s_, 16); s_ += __shfl_xor(s_, 32);
    float mean = s_ * (1.f / 64.f);
    float v_ = 0.f;
#pragma unroll
    for (int cb = 0; cb < 4; ++cb)
        for (int j = 0; j < 4; ++j) { float d = x1[cb][j] - mean; v_ += d * d; }
    v_ += __shfl_xor(v_, 16); v_ += __shfl_xor(v_, 32);
    float rstd = rsqrtf(v_ * (1.f / 64.f) + 1e-5f);

    float xh[4][4];
#pragma unroll
    for (int cb = 0; cb < 4; ++cb) {
        float4 lw = *(const float4*)&ln1w[cb * 16 + g * 4];
        float4 lb = *(const float4*)&ln1b[cb * 16 + g * 4];
        xh[cb][0] = (x1[cb][0] - mean) * rstd * lw.x + lb.x;
        xh[cb][1] = (x1[cb][1] - mean) * rstd * lw.y + lb.y;
        xh[cb][2] = (x1[cb][2] - mean) * rstd * lw.z + lb.z;
        xh[cb][3] = (x1[cb][3] - mean) * rstd * lw.w + lb.w;
    }

    // FFN layer 1 via LDS roundtrip (wave 0 only)
    u32* sXu = (u32*)sX;
    const int xwr = q * 32;
#pragma unroll
    for (int cb = 0; cb < 4; ++cb) {
        sXu[xwr + cb * 8 + g * 2 + 0] = pack2(xh[cb][0], xh[cb][1]);
        sXu[xwr + cb * 8 + g * 2 + 1] = pack2(xh[cb][2], xh[cb][3]);
    }
    asm volatile("s_waitcnt lgkmcnt(0)" ::: "memory");
    __builtin_amdgcn_sched_barrier(0);
    const u16* xrp = &sX[q * 64 + g * 8];
    bf16x8 xb0 = *(const bf16x8*)&xrp[0];
    bf16x8 xb1 = *(const bf16x8*)&xrp[32];

    float h[4][4];
#pragma unroll
    for (int ob = 0; ob < 4; ++ob) {
        float4 bb = *(const float4*)&b1[ob * 16 + g * 4];
        f32x4 hacc = {bb.x, bb.y, bb.z, bb.w};
        bf16x8 w0 = cvt8(&W1[(size_t)(ob * 16 + q) * 64 + g * 8]);
        bf16x8 w1 = cvt8(&W1[(size_t)(ob * 16 + q) * 64 + 32 + g * 8]);
        hacc = __builtin_amdgcn_mfma_f32_16x16x32_bf16(w0, xb0, hacc, 0, 0, 0);
        hacc = __builtin_amdgcn_mfma_f32_16x16x32_bf16(w1, xb1, hacc, 0, 0, 0);
#pragma unroll
        for (int j = 0; j < 4; ++j) h[ob][j] = fmaxf(hacc[j], 0.f);
    }

#pragma unroll
    for (int ob = 0; ob < 4; ++ob) {
        sXu[xwr + ob * 8 + g * 2 + 0] = pack2(h[ob][0], h[ob][1]);
        sXu[xwr + ob * 8 + g * 2 + 1] = pack2(h[ob][2], h[ob][3]);
    }
    asm volatile("s_waitcnt lgkmcnt(0)" ::: "memory");
    __builtin_amdgcn_sched_barrier(0);
    bf16x8 hb0 = *(const bf16x8*)&xrp[0];
    bf16x8 hb1 = *(const bf16x8*)&xrp[32];

    float f_[4][4];
#pragma unroll
    for (int cb = 0; cb < 4; ++cb) {
        float4 bb = *(const float4*)&b2[cb * 16 + g * 4];
        f32x4 yacc = {bb.x, bb.y, bb.z, bb.w};
        bf16x8 w0 = cvt8(&W2[(size_t)(cb * 16 + q) * 64 + g * 8]);
        bf16x8 w1 = cvt8(&W2[(size_t)(cb * 16 + q) * 64 + 32 + g * 8]);
        yacc = __builtin_amdgcn_mfma_f32_16x16x32_bf16(w0, hb0, yacc, 0, 0, 0);
        yacc = __builtin_amdgcn_mfma_f32_16x16x32_bf16(w1, hb1, yacc, 0, 0, 0);
#pragma unroll
        for (int j = 0; j < 4; ++j) f_[cb][j] = xh[cb][j] + yacc[j];
    }

    // LN2
    float s2 = 0.f;
#pragma unroll
    for (int cb = 0; cb < 4; ++cb)
        for (int j = 0; j < 4; ++j) s2 += f_[cb][j];
    s2 += __shfl_xor(s2, 16); s2 += __shfl_xor(s2, 32);
    float mean2 = s2 * (1.f / 64.f);
    float v2 = 0.f;
#pragma unroll
    for (int cb = 0; cb < 4; ++cb)
        for (int j = 0; j < 4; ++j) { float d = f_[cb][j] - mean2; v2 += d * d; }
    v2 += __shfl_xor(v2, 16); v2 += __shfl_xor(v2, 32);
    float rstd2 = rsqrtf(v2 * (1.f / 64.f) + 1e-5f);

#pragma unroll
    for (int cb = 0; cb < 4; ++cb) {
        float4 lw = *(const float4*)&ln2w[cb * 16 + g * 4];
        float4 lb = *(const float4*)&ln2b[cb * 16 + g * 4];
        float o0 = (f_[cb][0] - mean2) * rstd2 * lw.x + lb.x;
        float o1 = (f_[cb][1] - mean2) * rstd2 * lw.y + lb.y;
        float o2 = (f_[cb][2] - mean2) * rstd2 * lw.z + lb.z;
        float o3 = (f_[cb][3] - mean2) * rstd2 * lw.w + lb.w;
        out[(size_t)(b * 64 + cb * 16 + g * 4 + 0) * NTOK + n_q] = o0;
        out[(size_t)(b * 64 + cb * 16 + g * 4 + 1) * NTOK + n_q] = o1;
        out[(size_t)(b * 64 + cb * 16 + g * 4 + 2) * NTOK + n_q] = o2;
        out[(size_t)(b * 64 + cb * 16 + g * 4 + 3) * NTOK + n_q] = o3;
    }
}

extern "C" void kernel_launch(void* const* d_in, const int* in_sizes, int n_in,
                              void* d_out, int out_size, void* d_ws, size_t ws_size,
                              hipStream_t stream) {
    const float* seg = (const float*)d_in[0];
    const float* gau = (const float*)d_in[1];
    const float* Wq = (const float*)d_in[2];
    const float* bq = (const float*)d_in[3];
    const float* Wk = (const float*)d_in[4];
    const float* bk = (const float*)d_in[5];
    const float* Wv = (const float*)d_in[6];
    const float* bv = (const float*)d_in[7];
    const float* ln1w = (const float*)d_in[8];
    const float* ln1b = (const float*)d_in[9];
    const float* ln2w = (const float*)d_in[10];
    const float* ln2b = (const float*)d_in[11];
    const float* W1 = (const float*)d_in[12];
    const float* b1 = (const float*)d_in[13];
    const float* W2 = (const float*)d_in[14];
    const float* b2 = (const float*)d_in[15];

    u16* Qt = (u16*)d_ws;
    u16* Kt = Qt + (size_t)4 * NTOK * 64;
    u16* Vtok = Kt + (size_t)4 * NTOK * 64;
    u16* Vchan = Vtok + (size_t)4 * NTOK * 64;
    float* outp = (float*)d_out;

    dim3 gq(64, 4), bq_(512);
    hipLaunchKernelGGL(qkv_kernel, gq, bq_, 0, stream,
                       seg, gau, Wq, bq, Wk, bk, Wv, bv, Qt, Kt, Vtok, Vchan);
    dim3 ga(256, 4), ba(256);
    hipLaunchKernelGGL(attn_kernel, ga, ba, 0, stream,
                       Qt, Kt, Vtok, Vchan, ln1w, ln1b, ln2w, ln2b,
                       W1, b1, W2, b2, outp);
}

// Round 4
// 99.564 us; speedup vs baseline: 1.9625x; 1.9625x over previous
//
#include <hip/hip_runtime.h>

typedef unsigned short u16;
typedef unsigned int u32;
typedef __attribute__((ext_vector_type(8))) short bf16x8;
typedef __attribute__((ext_vector_type(4))) float f32x4;

#define NTOK 4096

__device__ __forceinline__ float b2f(u16 u) {
    u32 v = ((u32)u) << 16;
    return __builtin_bit_cast(float, v);
}
__device__ __forceinline__ u16 f2b(float f) {
    u32 u = __builtin_bit_cast(u32, f);
    u32 r = (u + 0x7fffu + ((u >> 16) & 1u)) >> 16;  // RNE
    return (u16)r;
}
__device__ __forceinline__ u32 pack2(float lo, float hi) {
    return (u32)f2b(lo) | ((u32)f2b(hi) << 16);
}
__device__ __forceinline__ bf16x8 cvt8(const float* __restrict__ p) {
    float4 a = *(const float4*)p;
    float4 b = *(const float4*)(p + 4);
    bf16x8 r;
    r[0] = (short)f2b(a.x); r[1] = (short)f2b(a.y);
    r[2] = (short)f2b(a.z); r[3] = (short)f2b(a.w);
    r[4] = (short)f2b(b.x); r[5] = (short)f2b(b.y);
    r[6] = (short)f2b(b.z); r[7] = (short)f2b(b.w);
    return r;
}

// ---------------------------------------------------------------------------
// Kernel 1: QKV projection. grid (64,4) blocks of 512 threads (8 waves).
// Waves 0-3: Q,K GEMMs for token group (wv&3); waves 4-7: V GEMM + stores.
// V is stored twice: token-major Vtok [B,N,64] (residual) and PRE-SWIZZLED
// Vswz in exact PV A-fragment order: [b][key_block(128)][cb(4)][lane(64)][8],
// so kernel 2 reads one coalesced 16B/lane load per channel block.
// Mapping: tile elem (lane, e) = V[channel cb*16+(lane&15)]
//          [key (e>>2)*16 + (lane>>4)*4 + (e&3)]  (same k-slot map as P).
// ---------------------------------------------------------------------------
__global__ __launch_bounds__(512) void qkv_kernel(
    const float* __restrict__ seg, const float* __restrict__ gau,
    const float* __restrict__ Wq, const float* __restrict__ bq,
    const float* __restrict__ Wk, const float* __restrict__ bk,
    const float* __restrict__ Wv, const float* __restrict__ bv,
    u16* __restrict__ Qt, u16* __restrict__ Kt,
    u16* __restrict__ Vtok, u16* __restrict__ Vswz)
{
    __shared__ __align__(16) u16 sSegT[64 * 64];
    __shared__ __align__(16) u16 sGauT[64 * 64];
    const int tid = threadIdx.x;
    const int b = blockIdx.y;
    const int n0 = blockIdx.x * 64;

    // load [c][n] coalesced fp32, store transposed [tok][c] bf16, XOR swizzle
    for (int idx = tid; idx < 4096; idx += 512) {
        int c = idx >> 6, t = idx & 63;
        int sw = t * 64 + ((((c >> 3) ^ (t & 7)) << 3) | (c & 7));
        sSegT[sw] = f2b(seg[(size_t)(b * 64 + c) * NTOK + n0 + t]);
        sGauT[sw] = f2b(gau[(size_t)(b * 64 + c) * NTOK + n0 + t]);
    }
    __syncthreads();

    const int lane = tid & 63;
    const int wv = tid >> 6;          // 0..7
    const int tb = wv & 3;            // token group
    const int task = wv >> 2;         // 0: Q,K   1: V
    const int q = lane & 15, g = lane >> 4;
    const int tok = tb * 16 + q;

    const size_t obase = (size_t)b * NTOK * 64;
    const size_t rowb = (size_t)(n0 + tb * 16 + g * 4);

    if (task == 0) {
        bf16x8 as[2];
#pragma unroll
        for (int ks = 0; ks < 2; ++ks) {
            int c0 = ks * 32 + g * 8;
            int sw = tok * 64 + (((c0 >> 3) ^ (tok & 7)) << 3);
            as[ks] = *(const bf16x8*)&sSegT[sw];
        }
#pragma unroll
        for (int ob = 0; ob < 4; ++ob) {
            int o = ob * 16 + q;
            {
                float bias = bq[o];
                f32x4 acc = {bias, bias, bias, bias};
                bf16x8 w0 = cvt8(&Wq[o * 64 + g * 8]);
                bf16x8 w1 = cvt8(&Wq[o * 64 + 32 + g * 8]);
                acc = __builtin_amdgcn_mfma_f32_16x16x32_bf16(as[0], w0, acc, 0, 0, 0);
                acc = __builtin_amdgcn_mfma_f32_16x16x32_bf16(as[1], w1, acc, 0, 0, 0);
#pragma unroll
                for (int j = 0; j < 4; ++j)
                    Qt[obase + (rowb + j) * 64 + o] = f2b(acc[j]);
            }
            {
                float bias = bk[o];
                f32x4 acc = {bias, bias, bias, bias};
                bf16x8 w0 = cvt8(&Wk[o * 64 + g * 8]);
                bf16x8 w1 = cvt8(&Wk[o * 64 + 32 + g * 8]);
                acc = __builtin_amdgcn_mfma_f32_16x16x32_bf16(as[0], w0, acc, 0, 0, 0);
                acc = __builtin_amdgcn_mfma_f32_16x16x32_bf16(as[1], w1, acc, 0, 0, 0);
#pragma unroll
                for (int j = 0; j < 4; ++j)
                    Kt[obase + (rowb + j) * 64 + o] = f2b(acc[j]);
            }
        }
    } else {
        bf16x8 ag[2];
#pragma unroll
        for (int ks = 0; ks < 2; ++ks) {
            int c0 = ks * 32 + g * 8;
            int sw = tok * 64 + (((c0 >> 3) ^ (tok & 7)) << 3);
            ag[ks] = *(const bf16x8*)&sGauT[sw];
        }
        const int kbg = (n0 >> 5) + (tb >> 1);   // global 32-key block
        const int half = tb & 1;                  // lo/hi 16 keys of the block
#pragma unroll
        for (int ob = 0; ob < 4; ++ob) {
            int o = ob * 16 + q;
            float bias = bv[o];
            f32x4 acc = {bias, bias, bias, bias};
            bf16x8 w0 = cvt8(&Wv[o * 64 + g * 8]);
            bf16x8 w1 = cvt8(&Wv[o * 64 + 32 + g * 8]);
            acc = __builtin_amdgcn_mfma_f32_16x16x32_bf16(ag[0], w0, acc, 0, 0, 0);
            acc = __builtin_amdgcn_mfma_f32_16x16x32_bf16(ag[1], w1, acc, 0, 0, 0);
            ushort4 v4;
            v4.x = f2b(acc[0]); v4.y = f2b(acc[1]);
            v4.z = f2b(acc[2]); v4.w = f2b(acc[3]);
#pragma unroll
            for (int j = 0; j < 4; ++j)
                Vtok[obase + (rowb + j) * 64 + o] = f2b(acc[j]);
            // pre-swizzled fragment store: producer lane == consumer lane
            *(ushort4*)&Vswz[(((size_t)(b * 128 + kbg)) * 4 + ob) * 512 + lane * 8 + half * 4] = v4;
        }
    }
}

// ---------------------------------------------------------------------------
// Kernel 2: flash attention (in-block K-split x4) + LN1 + FFN + LN2.
// grid (256,4), 256 threads = 4 waves sharing the SAME 16 queries; wave wv
// owns keys [wv*1024, wv*1024+1024). Hot loop: NO LDS, P in registers,
// V read as pre-swizzled coalesced fragments. Partials combined in LDS;
// wave 0 runs the fused epilogue.
// ---------------------------------------------------------------------------
__global__ __launch_bounds__(256, 4) void attn_kernel(
    const u16* __restrict__ Qt, const u16* __restrict__ Kt,
    const u16* __restrict__ Vtok, const u16* __restrict__ Vswz,
    const float* __restrict__ ln1w, const float* __restrict__ ln1b,
    const float* __restrict__ ln2w, const float* __restrict__ ln2b,
    const float* __restrict__ W1, const float* __restrict__ b1,
    const float* __restrict__ W2, const float* __restrict__ b2,
    float* __restrict__ out)
{
    __shared__ __align__(16) float sAcc[4][16][68];  // [wv][q][ch], pad 68
    __shared__ float sM[4][16], sL[4][16];
    __shared__ __align__(16) u16 sX[16 * 64];        // wave-0 FFN roundtrip

    const int tid = threadIdx.x;
    const int wv = tid >> 6;
    const int lane = tid & 63;
    const int q = lane & 15, g = lane >> 4;
    const int b = blockIdx.y;
    const int q0 = blockIdx.x * 16;
    const int n_q = q0 + q;
    const size_t tb_ = (size_t)b * NTOK * 64;

    // Q fragments (B-operand: col = query, k = channel)
    bf16x8 qf0 = *(const bf16x8*)&Qt[tb_ + (size_t)n_q * 64 + g * 8];
    bf16x8 qf1 = *(const bf16x8*)&Qt[tb_ + (size_t)n_q * 64 + 32 + g * 8];

    f32x4 zero4 = {0.f, 0.f, 0.f, 0.f};
    f32x4 acc[4];
#pragma unroll
    for (int i = 0; i < 4; ++i) acc[i] = zero4;
    float m = -1e30f, l = 0.f;

    const int kbeg = wv * 1024;
    const u16* Kp = &Kt[tb_ + (size_t)kbeg * 64];
    // pre-swizzled V: one 16B/lane coalesced load per channel block
    const u16* Vsw = Vswz + ((size_t)(b * 128 + (kbeg >> 5)) * 4) * 512 + lane * 8;

    for (int kk = 0; kk < 1024; kk += 32) {
        bf16x8 kf00 = *(const bf16x8*)&Kp[q * 64 + g * 8];
        bf16x8 kf01 = *(const bf16x8*)&Kp[q * 64 + 32 + g * 8];
        bf16x8 kf10 = *(const bf16x8*)&Kp[(16 + q) * 64 + g * 8];
        bf16x8 kf11 = *(const bf16x8*)&Kp[(16 + q) * 64 + 32 + g * 8];
        Kp += 32 * 64;

        const u16* vt = Vsw + (size_t)(kk >> 5) * 4 * 512;
        bf16x8 vf0 = *(const bf16x8*)&vt[0 * 512];
        bf16x8 vf1 = *(const bf16x8*)&vt[1 * 512];
        bf16x8 vf2 = *(const bf16x8*)&vt[2 * 512];
        bf16x8 vf3 = *(const bf16x8*)&vt[3 * 512];

        f32x4 s0 = __builtin_amdgcn_mfma_f32_16x16x32_bf16(kf00, qf0, zero4, 0, 0, 0);
        s0 = __builtin_amdgcn_mfma_f32_16x16x32_bf16(kf01, qf1, s0, 0, 0, 0);
        f32x4 s1 = __builtin_amdgcn_mfma_f32_16x16x32_bf16(kf10, qf0, zero4, 0, 0, 0);
        s1 = __builtin_amdgcn_mfma_f32_16x16x32_bf16(kf11, qf1, s1, 0, 0, 0);

        // lane holds S[q][kbeg+kk + g*4+j] (s0) and [... +16+g*4+j] (s1)
        float sv[8];
#pragma unroll
        for (int j = 0; j < 4; ++j) { sv[j] = s0[j] * 0.125f; sv[4 + j] = s1[j] * 0.125f; }

        float tm = sv[0];
#pragma unroll
        for (int j = 1; j < 8; ++j) tm = fmaxf(tm, sv[j]);
        tm = fmaxf(tm, __shfl_xor(tm, 16));
        tm = fmaxf(tm, __shfl_xor(tm, 32));

        float mn = fmaxf(m, tm);
        float corr = __expf(m - mn);
        m = mn;

        float p[8];
        float ps = 0.f;
#pragma unroll
        for (int j = 0; j < 8; ++j) { p[j] = __expf(sv[j] - mn); ps += p[j]; }
        ps += __shfl_xor(ps, 16);
        ps += __shfl_xor(ps, 32);
        l = l * corr + ps;
#pragma unroll
        for (int i = 0; i < 4; ++i) acc[i] *= corr;

        // P packed in-register as the PV B-operand (same k-slot map as Vswz)
        u32 pwv[4] = {pack2(p[0], p[1]), pack2(p[2], p[3]),
                      pack2(p[4], p[5]), pack2(p[6], p[7])};
        bf16x8 pf = __builtin_bit_cast(bf16x8, *(const bf16x8*)pwv);

        acc[0] = __builtin_amdgcn_mfma_f32_16x16x32_bf16(vf0, pf, acc[0], 0, 0, 0);
        acc[1] = __builtin_amdgcn_mfma_f32_16x16x32_bf16(vf1, pf, acc[1], 0, 0, 0);
        acc[2] = __builtin_amdgcn_mfma_f32_16x16x32_bf16(vf2, pf, acc[2], 0, 0, 0);
        acc[3] = __builtin_amdgcn_mfma_f32_16x16x32_bf16(vf3, pf, acc[3], 0, 0, 0);
    }

    // ---- write per-wave partials, combine in wave 0 ----
    sM[wv][q] = m;
    sL[wv][q] = l;
#pragma unroll
    for (int cb = 0; cb < 4; ++cb)
        *(f32x4*)&sAcc[wv][q][cb * 16 + g * 4] = acc[cb];
    __syncthreads();
    if (wv != 0) return;

    float m0 = sM[0][q], m1 = sM[1][q], m2 = sM[2][q], m3 = sM[3][q];
    float M = fmaxf(fmaxf(m0, m1), fmaxf(m2, m3));
    float c0 = __expf(m0 - M), c1 = __expf(m1 - M);
    float c2 = __expf(m2 - M), c3 = __expf(m3 - M);
    float L = c0 * sL[0][q] + c1 * sL[1][q] + c2 * sL[2][q] + c3 * sL[3][q];

    f32x4 o[4];
#pragma unroll
    for (int cb = 0; cb < 4; ++cb) {
        f32x4 a0 = *(const f32x4*)&sAcc[0][q][cb * 16 + g * 4];
        f32x4 a1 = *(const f32x4*)&sAcc[1][q][cb * 16 + g * 4];
        f32x4 a2 = *(const f32x4*)&sAcc[2][q][cb * 16 + g * 4];
        f32x4 a3 = *(const f32x4*)&sAcc[3][q][cb * 16 + g * 4];
#pragma unroll
        for (int j = 0; j < 4; ++j)
            o[cb][j] = c0 * a0[j] + c1 * a1[j] + c2 * a2[j] + c3 * a3[j];
    }

    // ---- epilogue: lane owns channels cb*16 + g*4 + j of query n_q ----
    float inv_l = 1.0f / L;
    float x1[4][4];
#pragma unroll
    for (int cb = 0; cb < 4; ++cb) {
        ushort4 vv = *(const ushort4*)&Vtok[tb_ + (size_t)n_q * 64 + cb * 16 + g * 4];
        x1[cb][0] = o[cb][0] * inv_l + b2f(vv.x);
        x1[cb][1] = o[cb][1] * inv_l + b2f(vv.y);
        x1[cb][2] = o[cb][2] * inv_l + b2f(vv.z);
        x1[cb][3] = o[cb][3] * inv_l + b2f(vv.w);
    }

    // LN1
    float s_ = 0.f;
#pragma unroll
    for (int cb = 0; cb < 4; ++cb)
        for (int j = 0; j < 4; ++j) s_ += x1[cb][j];
    s_ += __shfl_xor(s_, 16); s_ += __shfl_xor(s_, 32);
    float mean = s_ * (1.f / 64.f);
    float v_ = 0.f;
#pragma unroll
    for (int cb = 0; cb < 4; ++cb)
        for (int j = 0; j < 4; ++j) { float d = x1[cb][j] - mean; v_ += d * d; }
    v_ += __shfl_xor(v_, 16); v_ += __shfl_xor(v_, 32);
    float rstd = rsqrtf(v_ * (1.f / 64.f) + 1e-5f);

    float xh[4][4];
#pragma unroll
    for (int cb = 0; cb < 4; ++cb) {
        float4 lw = *(const float4*)&ln1w[cb * 16 + g * 4];
        float4 lb = *(const float4*)&ln1b[cb * 16 + g * 4];
        xh[cb][0] = (x1[cb][0] - mean) * rstd * lw.x + lb.x;
        xh[cb][1] = (x1[cb][1] - mean) * rstd * lw.y + lb.y;
        xh[cb][2] = (x1[cb][2] - mean) * rstd * lw.z + lb.z;
        xh[cb][3] = (x1[cb][3] - mean) * rstd * lw.w + lb.w;
    }

    // FFN layer 1 via LDS roundtrip (wave 0 only)
    u32* sXu = (u32*)sX;
    const int xwr = q * 32;
#pragma unroll
    for (int cb = 0; cb < 4; ++cb) {
        sXu[xwr + cb * 8 + g * 2 + 0] = pack2(xh[cb][0], xh[cb][1]);
        sXu[xwr + cb * 8 + g * 2 + 1] = pack2(xh[cb][2], xh[cb][3]);
    }
    asm volatile("s_waitcnt lgkmcnt(0)" ::: "memory");
    __builtin_amdgcn_sched_barrier(0);
    const u16* xrp = &sX[q * 64 + g * 8];
    bf16x8 xb0 = *(const bf16x8*)&xrp[0];
    bf16x8 xb1 = *(const bf16x8*)&xrp[32];

    float h[4][4];
#pragma unroll
    for (int ob = 0; ob < 4; ++ob) {
        float4 bb = *(const float4*)&b1[ob * 16 + g * 4];
        f32x4 hacc = {bb.x, bb.y, bb.z, bb.w};
        bf16x8 w0 = cvt8(&W1[(size_t)(ob * 16 + q) * 64 + g * 8]);
        bf16x8 w1 = cvt8(&W1[(size_t)(ob * 16 + q) * 64 + 32 + g * 8]);
        hacc = __builtin_amdgcn_mfma_f32_16x16x32_bf16(w0, xb0, hacc, 0, 0, 0);
        hacc = __builtin_amdgcn_mfma_f32_16x16x32_bf16(w1, xb1, hacc, 0, 0, 0);
#pragma unroll
        for (int j = 0; j < 4; ++j) h[ob][j] = fmaxf(hacc[j], 0.f);
    }

#pragma unroll
    for (int ob = 0; ob < 4; ++ob) {
        sXu[xwr + ob * 8 + g * 2 + 0] = pack2(h[ob][0], h[ob][1]);
        sXu[xwr + ob * 8 + g * 2 + 1] = pack2(h[ob][2], h[ob][3]);
    }
    asm volatile("s_waitcnt lgkmcnt(0)" ::: "memory");
    __builtin_amdgcn_sched_barrier(0);
    bf16x8 hb0 = *(const bf16x8*)&xrp[0];
    bf16x8 hb1 = *(const bf16x8*)&xrp[32];

    float f_[4][4];
#pragma unroll
    for (int cb = 0; cb < 4; ++cb) {
        float4 bb = *(const float4*)&b2[cb * 16 + g * 4];
        f32x4 yacc = {bb.x, bb.y, bb.z, bb.w};
        bf16x8 w0 = cvt8(&W2[(size_t)(cb * 16 + q) * 64 + g * 8]);
        bf16x8 w1 = cvt8(&W2[(size_t)(cb * 16 + q) * 64 + 32 + g * 8]);
        yacc = __builtin_amdgcn_mfma_f32_16x16x32_bf16(w0, hb0, yacc, 0, 0, 0);
        yacc = __builtin_amdgcn_mfma_f32_16x16x32_bf16(w1, hb1, yacc, 0, 0, 0);
#pragma unroll
        for (int j = 0; j < 4; ++j) f_[cb][j] = xh[cb][j] + yacc[j];
    }

    // LN2
    float s2 = 0.f;
#pragma unroll
    for (int cb = 0; cb < 4; ++cb)
        for (int j = 0; j < 4; ++j) s2 += f_[cb][j];
    s2 += __shfl_xor(s2, 16); s2 += __shfl_xor(s2, 32);
    float mean2 = s2 * (1.f / 64.f);
    float v2 = 0.f;
#pragma unroll
    for (int cb = 0; cb < 4; ++cb)
        for (int j = 0; j < 4; ++j) { float d = f_[cb][j] - mean2; v2 += d * d; }
    v2 += __shfl_xor(v2, 16); v2 += __shfl_xor(v2, 32);
    float rstd2 = rsqrtf(v2 * (1.f / 64.f) + 1e-5f);

#pragma unroll
    for (int cb = 0; cb < 4; ++cb) {
        float4 lw = *(const float4*)&ln2w[cb * 16 + g * 4];
        float4 lb = *(const float4*)&ln2b[cb * 16 + g * 4];
        float o0 = (f_[cb][0] - mean2) * rstd2 * lw.x + lb.x;
        float o1 = (f_[cb][1] - mean2) * rstd2 * lw.y + lb.y;
        float o2 = (f_[cb][2] - mean2) * rstd2 * lw.z + lb.z;
        float o3 = (f_[cb][3] - mean2) * rstd2 * lw.w + lb.w;
        out[(size_t)(b * 64 + cb * 16 + g * 4 + 0) * NTOK + n_q] = o0;
        out[(size_t)(b * 64 + cb * 16 + g * 4 + 1) * NTOK + n_q] = o1;
        out[(size_t)(b * 64 + cb * 16 + g * 4 + 2) * NTOK + n_q] = o2;
        out[(size_t)(b * 64 + cb * 16 + g * 4 + 3) * NTOK + n_q] = o3;
    }
}

extern "C" void kernel_launch(void* const* d_in, const int* in_sizes, int n_in,
                              void* d_out, int out_size, void* d_ws, size_t ws_size,
                              hipStream_t stream) {
    const float* seg = (const float*)d_in[0];
    const float* gau = (const float*)d_in[1];
    const float* Wq = (const float*)d_in[2];
    const float* bq = (const float*)d_in[3];
    const float* Wk = (const float*)d_in[4];
    const float* bk = (const float*)d_in[5];
    const float* Wv = (const float*)d_in[6];
    const float* bv = (const float*)d_in[7];
    const float* ln1w = (const float*)d_in[8];
    const float* ln1b = (const float*)d_in[9];
    const float* ln2w = (const float*)d_in[10];
    const float* ln2b = (const float*)d_in[11];
    const float* W1 = (const float*)d_in[12];
    const float* b1 = (const float*)d_in[13];
    const float* W2 = (const float*)d_in[14];
    const float* b2 = (const float*)d_in[15];

    u16* Qt = (u16*)d_ws;
    u16* Kt = Qt + (size_t)4 * NTOK * 64;
    u16* Vtok = Kt + (size_t)4 * NTOK * 64;
    u16* Vswz = Vtok + (size_t)4 * NTOK * 64;   // [b][kb(128)][cb(4)][lane(64)][8]
    float* outp = (float*)d_out;

    dim3 gq(64, 4), bq_(512);
    hipLaunchKernelGGL(qkv_kernel, gq, bq_, 0, stream,
                       seg, gau, Wq, bq, Wk, bk, Wv, bv, Qt, Kt, Vtok, Vswz);
    dim3 ga(256, 4), ba(256);
    hipLaunchKernelGGL(attn_kernel, ga, ba, 0, stream,
                       Qt, Kt, Vtok, Vswz, ln1w, ln1b, ln2w, ln2b,
                       W1, b1, W2, b2, outp);
}

// Round 5
// 64.901 us; speedup vs baseline: 3.0107x; 1.5341x over previous
//
#include <hip/hip_runtime.h>

typedef unsigned short u16;
typedef unsigned int u32;
typedef __attribute__((ext_vector_type(8))) short bf16x8;
typedef __attribute__((ext_vector_type(4))) float f32x4;

#define NTOK 4096

__device__ __forceinline__ float b2f(u16 u) {
    u32 v = ((u32)u) << 16;
    return __builtin_bit_cast(float, v);
}
__device__ __forceinline__ u16 f2b(float f) {
    u32 u = __builtin_bit_cast(u32, f);
    u32 r = (u + 0x7fffu + ((u >> 16) & 1u)) >> 16;  // RNE
    return (u16)r;
}
__device__ __forceinline__ u32 pack2(float lo, float hi) {
    return (u32)f2b(lo) | ((u32)f2b(hi) << 16);
}
__device__ __forceinline__ bf16x8 cvt8(const float* __restrict__ p) {
    float4 a = *(const float4*)p;
    float4 b = *(const float4*)(p + 4);
    bf16x8 r;
    r[0] = (short)f2b(a.x); r[1] = (short)f2b(a.y);
    r[2] = (short)f2b(a.z); r[3] = (short)f2b(a.w);
    r[4] = (short)f2b(b.x); r[5] = (short)f2b(b.y);
    r[6] = (short)f2b(b.z); r[7] = (short)f2b(b.w);
    return r;
}

// ---------------------------------------------------------------------------
// Kernel 1: QKV projection. 1-D grid of 256 blocks (512 threads), decoded
// with XCD affinity: batch b = (bid&7)>>1 so each batch's K/V writes land on
// 2 XCDs' L2s (same decode as the consumer kernel).
// Waves 0-3: Q,K GEMMs; waves 4-7: V GEMM + stores (Vtok + pre-swizzled Vswz
// in exact PV A-fragment order [b][kb(128)][cb(4)][lane(64)][8]).
// ---------------------------------------------------------------------------
__global__ __launch_bounds__(512) void qkv_kernel(
    const float* __restrict__ seg, const float* __restrict__ gau,
    const float* __restrict__ Wq, const float* __restrict__ bq,
    const float* __restrict__ Wk, const float* __restrict__ bk,
    const float* __restrict__ Wv, const float* __restrict__ bv,
    u16* __restrict__ Qt, u16* __restrict__ Kt,
    u16* __restrict__ Vtok, u16* __restrict__ Vswz)
{
    __shared__ __align__(16) u16 sSegT[64 * 64];
    __shared__ __align__(16) u16 sGauT[64 * 64];
    const int tid = threadIdx.x;
    const int bid = blockIdx.x;            // 0..255
    const int xcd = bid & 7;
    const int b = xcd >> 1;                // batch pinned to XCD pair
    const int nb = ((bid >> 3) << 1) | (xcd & 1);   // 0..63
    const int n0 = nb * 64;

    for (int idx = tid; idx < 4096; idx += 512) {
        int c = idx >> 6, t = idx & 63;
        int sw = t * 64 + ((((c >> 3) ^ (t & 7)) << 3) | (c & 7));
        sSegT[sw] = f2b(seg[(size_t)(b * 64 + c) * NTOK + n0 + t]);
        sGauT[sw] = f2b(gau[(size_t)(b * 64 + c) * NTOK + n0 + t]);
    }
    __syncthreads();

    const int lane = tid & 63;
    const int wv = tid >> 6;          // 0..7
    const int tb = wv & 3;            // token group
    const int task = wv >> 2;         // 0: Q,K   1: V
    const int q = lane & 15, g = lane >> 4;
    const int tok = tb * 16 + q;

    const size_t obase = (size_t)b * NTOK * 64;
    const size_t rowb = (size_t)(n0 + tb * 16 + g * 4);

    if (task == 0) {
        bf16x8 as[2];
#pragma unroll
        for (int ks = 0; ks < 2; ++ks) {
            int c0 = ks * 32 + g * 8;
            int sw = tok * 64 + (((c0 >> 3) ^ (tok & 7)) << 3);
            as[ks] = *(const bf16x8*)&sSegT[sw];
        }
#pragma unroll
        for (int ob = 0; ob < 4; ++ob) {
            int o = ob * 16 + q;
            {
                float bias = bq[o];
                f32x4 acc = {bias, bias, bias, bias};
                bf16x8 w0 = cvt8(&Wq[o * 64 + g * 8]);
                bf16x8 w1 = cvt8(&Wq[o * 64 + 32 + g * 8]);
                acc = __builtin_amdgcn_mfma_f32_16x16x32_bf16(as[0], w0, acc, 0, 0, 0);
                acc = __builtin_amdgcn_mfma_f32_16x16x32_bf16(as[1], w1, acc, 0, 0, 0);
#pragma unroll
                for (int j = 0; j < 4; ++j)
                    Qt[obase + (rowb + j) * 64 + o] = f2b(acc[j]);
            }
            {
                float bias = bk[o];
                f32x4 acc = {bias, bias, bias, bias};
                bf16x8 w0 = cvt8(&Wk[o * 64 + g * 8]);
                bf16x8 w1 = cvt8(&Wk[o * 64 + 32 + g * 8]);
                acc = __builtin_amdgcn_mfma_f32_16x16x32_bf16(as[0], w0, acc, 0, 0, 0);
                acc = __builtin_amdgcn_mfma_f32_16x16x32_bf16(as[1], w1, acc, 0, 0, 0);
#pragma unroll
                for (int j = 0; j < 4; ++j)
                    Kt[obase + (rowb + j) * 64 + o] = f2b(acc[j]);
            }
        }
    } else {
        bf16x8 ag[2];
#pragma unroll
        for (int ks = 0; ks < 2; ++ks) {
            int c0 = ks * 32 + g * 8;
            int sw = tok * 64 + (((c0 >> 3) ^ (tok & 7)) << 3);
            ag[ks] = *(const bf16x8*)&sGauT[sw];
        }
        const int kbg = (n0 >> 5) + (tb >> 1);
        const int half = tb & 1;
#pragma unroll
        for (int ob = 0; ob < 4; ++ob) {
            int o = ob * 16 + q;
            float bias = bv[o];
            f32x4 acc = {bias, bias, bias, bias};
            bf16x8 w0 = cvt8(&Wv[o * 64 + g * 8]);
            bf16x8 w1 = cvt8(&Wv[o * 64 + 32 + g * 8]);
            acc = __builtin_amdgcn_mfma_f32_16x16x32_bf16(ag[0], w0, acc, 0, 0, 0);
            acc = __builtin_amdgcn_mfma_f32_16x16x32_bf16(ag[1], w1, acc, 0, 0, 0);
            ushort4 v4;
            v4.x = f2b(acc[0]); v4.y = f2b(acc[1]);
            v4.z = f2b(acc[2]); v4.w = f2b(acc[3]);
#pragma unroll
            for (int j = 0; j < 4; ++j)
                Vtok[obase + (rowb + j) * 64 + o] = f2b(acc[j]);
            *(ushort4*)&Vswz[(((size_t)(b * 128 + kbg)) * 4 + ob) * 512 + lane * 8 + half * 4] = v4;
        }
    }
}

// ---------------------------------------------------------------------------
// Kernel 2: flash attention + LN1 + FFN + LN2.
// 1-D grid of 512 blocks (8 waves), XCD-affine decode: batch = (bid&7)>>1.
// Block = 32 queries; the 8 waves K-split 4096 keys (512 each). Each wave
// handles TWO 16-query groups sharing its K/V fragment loads (halves L2
// traffic vs r4). Defer-max (THR=8) skips the acc rescale on stable tiles.
// Partials combined in LDS; waves 0,1 run the fused epilogue (16 q each).
// ---------------------------------------------------------------------------
__global__ __launch_bounds__(512, 4) void attn_kernel(
    const u16* __restrict__ Qt, const u16* __restrict__ Kt,
    const u16* __restrict__ Vtok, const u16* __restrict__ Vswz,
    const float* __restrict__ ln1w, const float* __restrict__ ln1b,
    const float* __restrict__ ln2w, const float* __restrict__ ln2b,
    const float* __restrict__ W1, const float* __restrict__ b1,
    const float* __restrict__ W2, const float* __restrict__ b2,
    float* __restrict__ out)
{
    __shared__ __align__(16) float sAcc[8][32][68];
    __shared__ float sM[8][32], sL[8][32];
    __shared__ __align__(16) u16 sX[2 * 16 * 64];

    const int tid = threadIdx.x;
    const int wv = tid >> 6;          // 0..7 (K-split)
    const int lane = tid & 63;
    const int q = lane & 15, g = lane >> 4;
    const int bid = blockIdx.x;       // 0..511
    const int xcd = bid & 7;
    const int b = xcd >> 1;
    const int qb = ((bid >> 3) << 1) | (xcd & 1);   // 0..127
    const int q0 = qb * 32;
    const size_t tb_ = (size_t)b * NTOK * 64;

    // Q fragments for the two 16-query groups
    const int n_qa = q0 + q, n_qb = q0 + 16 + q;
    bf16x8 qa0 = *(const bf16x8*)&Qt[tb_ + (size_t)n_qa * 64 + g * 8];
    bf16x8 qa1 = *(const bf16x8*)&Qt[tb_ + (size_t)n_qa * 64 + 32 + g * 8];
    bf16x8 qb0 = *(const bf16x8*)&Qt[tb_ + (size_t)n_qb * 64 + g * 8];
    bf16x8 qb1 = *(const bf16x8*)&Qt[tb_ + (size_t)n_qb * 64 + 32 + g * 8];

    f32x4 zero4 = {0.f, 0.f, 0.f, 0.f};
    f32x4 acc_a[4], acc_b[4];
#pragma unroll
    for (int i = 0; i < 4; ++i) { acc_a[i] = zero4; acc_b[i] = zero4; }
    float m_a = -1e30f, l_a = 0.f, m_b = -1e30f, l_b = 0.f;

    const int kbeg = wv * 512;
    const u16* Kp = &Kt[tb_ + (size_t)kbeg * 64];
    const u16* Vsw = Vswz + ((size_t)(b * 128 + (kbeg >> 5)) * 4) * 512 + lane * 8;

    for (int kk = 0; kk < 512; kk += 32) {
        bf16x8 kf00 = *(const bf16x8*)&Kp[q * 64 + g * 8];
        bf16x8 kf01 = *(const bf16x8*)&Kp[q * 64 + 32 + g * 8];
        bf16x8 kf10 = *(const bf16x8*)&Kp[(16 + q) * 64 + g * 8];
        bf16x8 kf11 = *(const bf16x8*)&Kp[(16 + q) * 64 + 32 + g * 8];
        Kp += 32 * 64;

        const u16* vt = Vsw + (size_t)(kk >> 5) * 4 * 512;
        bf16x8 vf0 = *(const bf16x8*)&vt[0 * 512];
        bf16x8 vf1 = *(const bf16x8*)&vt[1 * 512];
        bf16x8 vf2 = *(const bf16x8*)&vt[2 * 512];
        bf16x8 vf3 = *(const bf16x8*)&vt[3 * 512];

        f32x4 s0a = __builtin_amdgcn_mfma_f32_16x16x32_bf16(kf00, qa0, zero4, 0, 0, 0);
        s0a = __builtin_amdgcn_mfma_f32_16x16x32_bf16(kf01, qa1, s0a, 0, 0, 0);
        f32x4 s1a = __builtin_amdgcn_mfma_f32_16x16x32_bf16(kf10, qa0, zero4, 0, 0, 0);
        s1a = __builtin_amdgcn_mfma_f32_16x16x32_bf16(kf11, qa1, s1a, 0, 0, 0);
        f32x4 s0b = __builtin_amdgcn_mfma_f32_16x16x32_bf16(kf00, qb0, zero4, 0, 0, 0);
        s0b = __builtin_amdgcn_mfma_f32_16x16x32_bf16(kf01, qb1, s0b, 0, 0, 0);
        f32x4 s1b = __builtin_amdgcn_mfma_f32_16x16x32_bf16(kf10, qb0, zero4, 0, 0, 0);
        s1b = __builtin_amdgcn_mfma_f32_16x16x32_bf16(kf11, qb1, s1b, 0, 0, 0);

        // ---- group a softmax (scale 0.125 folded into compare/exp) ----
        {
            float tm = fmaxf(fmaxf(fmaxf(s0a[0], s0a[1]), fmaxf(s0a[2], s0a[3])),
                             fmaxf(fmaxf(s1a[0], s1a[1]), fmaxf(s1a[2], s1a[3])));
            tm = fmaxf(tm, __shfl_xor(tm, 16));
            tm = fmaxf(tm, __shfl_xor(tm, 32));
            tm *= 0.125f;
            if (!__all(tm <= m_a + 8.f)) {
                float mn = fmaxf(m_a, tm);
                float corr = __expf(m_a - mn);
                l_a *= corr;
#pragma unroll
                for (int i = 0; i < 4; ++i) acc_a[i] *= corr;
                m_a = mn;
            }
            float p0 = __expf(fmaf(s0a[0], 0.125f, -m_a));
            float p1 = __expf(fmaf(s0a[1], 0.125f, -m_a));
            float p2 = __expf(fmaf(s0a[2], 0.125f, -m_a));
            float p3 = __expf(fmaf(s0a[3], 0.125f, -m_a));
            float p4 = __expf(fmaf(s1a[0], 0.125f, -m_a));
            float p5 = __expf(fmaf(s1a[1], 0.125f, -m_a));
            float p6 = __expf(fmaf(s1a[2], 0.125f, -m_a));
            float p7 = __expf(fmaf(s1a[3], 0.125f, -m_a));
            float ps = ((p0 + p1) + (p2 + p3)) + ((p4 + p5) + (p6 + p7));
            ps += __shfl_xor(ps, 16);
            ps += __shfl_xor(ps, 32);
            l_a += ps;
            u32 pwv[4] = {pack2(p0, p1), pack2(p2, p3), pack2(p4, p5), pack2(p6, p7)};
            bf16x8 pf = __builtin_bit_cast(bf16x8, *(const bf16x8*)pwv);
            acc_a[0] = __builtin_amdgcn_mfma_f32_16x16x32_bf16(vf0, pf, acc_a[0], 0, 0, 0);
            acc_a[1] = __builtin_amdgcn_mfma_f32_16x16x32_bf16(vf1, pf, acc_a[1], 0, 0, 0);
            acc_a[2] = __builtin_amdgcn_mfma_f32_16x16x32_bf16(vf2, pf, acc_a[2], 0, 0, 0);
            acc_a[3] = __builtin_amdgcn_mfma_f32_16x16x32_bf16(vf3, pf, acc_a[3], 0, 0, 0);
        }
        // ---- group b softmax ----
        {
            float tm = fmaxf(fmaxf(fmaxf(s0b[0], s0b[1]), fmaxf(s0b[2], s0b[3])),
                             fmaxf(fmaxf(s1b[0], s1b[1]), fmaxf(s1b[2], s1b[3])));
            tm = fmaxf(tm, __shfl_xor(tm, 16));
            tm = fmaxf(tm, __shfl_xor(tm, 32));
            tm *= 0.125f;
            if (!__all(tm <= m_b + 8.f)) {
                float mn = fmaxf(m_b, tm);
                float corr = __expf(m_b - mn);
                l_b *= corr;
#pragma unroll
                for (int i = 0; i < 4; ++i) acc_b[i] *= corr;
                m_b = mn;
            }
            float p0 = __expf(fmaf(s0b[0], 0.125f, -m_b));
            float p1 = __expf(fmaf(s0b[1], 0.125f, -m_b));
            float p2 = __expf(fmaf(s0b[2], 0.125f, -m_b));
            float p3 = __expf(fmaf(s0b[3], 0.125f, -m_b));
            float p4 = __expf(fmaf(s1b[0], 0.125f, -m_b));
            float p5 = __expf(fmaf(s1b[1], 0.125f, -m_b));
            float p6 = __expf(fmaf(s1b[2], 0.125f, -m_b));
            float p7 = __expf(fmaf(s1b[3], 0.125f, -m_b));
            float ps = ((p0 + p1) + (p2 + p3)) + ((p4 + p5) + (p6 + p7));
            ps += __shfl_xor(ps, 16);
            ps += __shfl_xor(ps, 32);
            l_b += ps;
            u32 pwv[4] = {pack2(p0, p1), pack2(p2, p3), pack2(p4, p5), pack2(p6, p7)};
            bf16x8 pf = __builtin_bit_cast(bf16x8, *(const bf16x8*)pwv);
            acc_b[0] = __builtin_amdgcn_mfma_f32_16x16x32_bf16(vf0, pf, acc_b[0], 0, 0, 0);
            acc_b[1] = __builtin_amdgcn_mfma_f32_16x16x32_bf16(vf1, pf, acc_b[1], 0, 0, 0);
            acc_b[2] = __builtin_amdgcn_mfma_f32_16x16x32_bf16(vf2, pf, acc_b[2], 0, 0, 0);
            acc_b[3] = __builtin_amdgcn_mfma_f32_16x16x32_bf16(vf3, pf, acc_b[3], 0, 0, 0);
        }
    }

    // ---- write per-wave partials ----
    sM[wv][q] = m_a;      sM[wv][16 + q] = m_b;
    sL[wv][q] = l_a;      sL[wv][16 + q] = l_b;
#pragma unroll
    for (int cb = 0; cb < 4; ++cb) {
        *(f32x4*)&sAcc[wv][q][cb * 16 + g * 4] = acc_a[cb];
        *(f32x4*)&sAcc[wv][16 + q][cb * 16 + g * 4] = acc_b[cb];
    }
    __syncthreads();
    if (wv >= 2) return;

    // waves 0,1: combine 8 partials for local queries qe = wv*16 + q
    const int qe = wv * 16 + q;
    const int n_q = q0 + qe;

    float M = sM[0][qe];
#pragma unroll
    for (int w = 1; w < 8; ++w) M = fmaxf(M, sM[w][qe]);
    float L = 0.f;
    f32x4 o[4];
#pragma unroll
    for (int cb = 0; cb < 4; ++cb) o[cb] = zero4;
#pragma unroll
    for (int w = 0; w < 8; ++w) {
        float c = __expf(sM[w][qe] - M);
        L += c * sL[w][qe];
#pragma unroll
        for (int cb = 0; cb < 4; ++cb) {
            f32x4 aw = *(const f32x4*)&sAcc[w][qe][cb * 16 + g * 4];
#pragma unroll
            for (int j = 0; j < 4; ++j) o[cb][j] += c * aw[j];
        }
    }

    // ---- epilogue: lane owns channels cb*16 + g*4 + j of query n_q ----
    float inv_l = 1.0f / L;
    float x1[4][4];
#pragma unroll
    for (int cb = 0; cb < 4; ++cb) {
        ushort4 vv = *(const ushort4*)&Vtok[tb_ + (size_t)n_q * 64 + cb * 16 + g * 4];
        x1[cb][0] = o[cb][0] * inv_l + b2f(vv.x);
        x1[cb][1] = o[cb][1] * inv_l + b2f(vv.y);
        x1[cb][2] = o[cb][2] * inv_l + b2f(vv.z);
        x1[cb][3] = o[cb][3] * inv_l + b2f(vv.w);
    }

    // LN1
    float s_ = 0.f;
#pragma unroll
    for (int cb = 0; cb < 4; ++cb)
        for (int j = 0; j < 4; ++j) s_ += x1[cb][j];
    s_ += __shfl_xor(s_, 16); s_ += __shfl_xor(s_, 32);
    float mean = s_ * (1.f / 64.f);
    float v_ = 0.f;
#pragma unroll
    for (int cb = 0; cb < 4; ++cb)
        for (int j = 0; j < 4; ++j) { float d = x1[cb][j] - mean; v_ += d * d; }
    v_ += __shfl_xor(v_, 16); v_ += __shfl_xor(v_, 32);
    float rstd = rsqrtf(v_ * (1.f / 64.f) + 1e-5f);

    float xh[4][4];
#pragma unroll
    for (int cb = 0; cb < 4; ++cb) {
        float4 lw = *(const float4*)&ln1w[cb * 16 + g * 4];
        float4 lb = *(const float4*)&ln1b[cb * 16 + g * 4];
        xh[cb][0] = (x1[cb][0] - mean) * rstd * lw.x + lb.x;
        xh[cb][1] = (x1[cb][1] - mean) * rstd * lw.y + lb.y;
        xh[cb][2] = (x1[cb][2] - mean) * rstd * lw.z + lb.z;
        xh[cb][3] = (x1[cb][3] - mean) * rstd * lw.w + lb.w;
    }

    // FFN layer 1 via per-wave LDS roundtrip
    u32* sXu = (u32*)sX;
    const int xwr = wv * 512 + q * 32;
#pragma unroll
    for (int cb = 0; cb < 4; ++cb) {
        sXu[xwr + cb * 8 + g * 2 + 0] = pack2(xh[cb][0], xh[cb][1]);
        sXu[xwr + cb * 8 + g * 2 + 1] = pack2(xh[cb][2], xh[cb][3]);
    }
    asm volatile("s_waitcnt lgkmcnt(0)" ::: "memory");
    __builtin_amdgcn_sched_barrier(0);
    const u16* xrp = &sX[wv * 1024 + q * 64 + g * 8];
    bf16x8 xb0 = *(const bf16x8*)&xrp[0];
    bf16x8 xb1 = *(const bf16x8*)&xrp[32];

    float h[4][4];
#pragma unroll
    for (int ob = 0; ob < 4; ++ob) {
        float4 bb = *(const float4*)&b1[ob * 16 + g * 4];
        f32x4 hacc = {bb.x, bb.y, bb.z, bb.w};
        bf16x8 w0 = cvt8(&W1[(size_t)(ob * 16 + q) * 64 + g * 8]);
        bf16x8 w1 = cvt8(&W1[(size_t)(ob * 16 + q) * 64 + 32 + g * 8]);
        hacc = __builtin_amdgcn_mfma_f32_16x16x32_bf16(w0, xb0, hacc, 0, 0, 0);
        hacc = __builtin_amdgcn_mfma_f32_16x16x32_bf16(w1, xb1, hacc, 0, 0, 0);
#pragma unroll
        for (int j = 0; j < 4; ++j) h[ob][j] = fmaxf(hacc[j], 0.f);
    }

#pragma unroll
    for (int ob = 0; ob < 4; ++ob) {
        sXu[xwr + ob * 8 + g * 2 + 0] = pack2(h[ob][0], h[ob][1]);
        sXu[xwr + ob * 8 + g * 2 + 1] = pack2(h[ob][2], h[ob][3]);
    }
    asm volatile("s_waitcnt lgkmcnt(0)" ::: "memory");
    __builtin_amdgcn_sched_barrier(0);
    bf16x8 hb0 = *(const bf16x8*)&xrp[0];
    bf16x8 hb1 = *(const bf16x8*)&xrp[32];

    float f_[4][4];
#pragma unroll
    for (int cb = 0; cb < 4; ++cb) {
        float4 bb = *(const float4*)&b2[cb * 16 + g * 4];
        f32x4 yacc = {bb.x, bb.y, bb.z, bb.w};
        bf16x8 w0 = cvt8(&W2[(size_t)(cb * 16 + q) * 64 + g * 8]);
        bf16x8 w1 = cvt8(&W2[(size_t)(cb * 16 + q) * 64 + 32 + g * 8]);
        yacc = __builtin_amdgcn_mfma_f32_16x16x32_bf16(w0, hb0, yacc, 0, 0, 0);
        yacc = __builtin_amdgcn_mfma_f32_16x16x32_bf16(w1, hb1, yacc, 0, 0, 0);
#pragma unroll
        for (int j = 0; j < 4; ++j) f_[cb][j] = xh[cb][j] + yacc[j];
    }

    // LN2
    float s2 = 0.f;
#pragma unroll
    for (int cb = 0; cb < 4; ++cb)
        for (int j = 0; j < 4; ++j) s2 += f_[cb][j];
    s2 += __shfl_xor(s2, 16); s2 += __shfl_xor(s2, 32);
    float mean2 = s2 * (1.f / 64.f);
    float v2 = 0.f;
#pragma unroll
    for (int cb = 0; cb < 4; ++cb)
        for (int j = 0; j < 4; ++j) { float d = f_[cb][j] - mean2; v2 += d * d; }
    v2 += __shfl_xor(v2, 16); v2 += __shfl_xor(v2, 32);
    float rstd2 = rsqrtf(v2 * (1.f / 64.f) + 1e-5f);

#pragma unroll
    for (int cb = 0; cb < 4; ++cb) {
        float4 lw = *(const float4*)&ln2w[cb * 16 + g * 4];
        float4 lb = *(const float4*)&ln2b[cb * 16 + g * 4];
        float o0 = (f_[cb][0] - mean2) * rstd2 * lw.x + lb.x;
        float o1 = (f_[cb][1] - mean2) * rstd2 * lw.y + lb.y;
        float o2 = (f_[cb][2] - mean2) * rstd2 * lw.z + lb.z;
        float o3 = (f_[cb][3] - mean2) * rstd2 * lw.w + lb.w;
        out[(size_t)(b * 64 + cb * 16 + g * 4 + 0) * NTOK + n_q] = o0;
        out[(size_t)(b * 64 + cb * 16 + g * 4 + 1) * NTOK + n_q] = o1;
        out[(size_t)(b * 64 + cb * 16 + g * 4 + 2) * NTOK + n_q] = o2;
        out[(size_t)(b * 64 + cb * 16 + g * 4 + 3) * NTOK + n_q] = o3;
    }
}

extern "C" void kernel_launch(void* const* d_in, const int* in_sizes, int n_in,
                              void* d_out, int out_size, void* d_ws, size_t ws_size,
                              hipStream_t stream) {
    const float* seg = (const float*)d_in[0];
    const float* gau = (const float*)d_in[1];
    const float* Wq = (const float*)d_in[2];
    const float* bq = (const float*)d_in[3];
    const float* Wk = (const float*)d_in[4];
    const float* bk = (const float*)d_in[5];
    const float* Wv = (const float*)d_in[6];
    const float* bv = (const float*)d_in[7];
    const float* ln1w = (const float*)d_in[8];
    const float* ln1b = (const float*)d_in[9];
    const float* ln2w = (const float*)d_in[10];
    const float* ln2b = (const float*)d_in[11];
    const float* W1 = (const float*)d_in[12];
    const float* b1 = (const float*)d_in[13];
    const float* W2 = (const float*)d_in[14];
    const float* b2 = (const float*)d_in[15];

    u16* Qt = (u16*)d_ws;
    u16* Kt = Qt + (size_t)4 * NTOK * 64;
    u16* Vtok = Kt + (size_t)4 * NTOK * 64;
    u16* Vswz = Vtok + (size_t)4 * NTOK * 64;   // [b][kb(128)][cb(4)][lane(64)][8]
    float* outp = (float*)d_out;

    hipLaunchKernelGGL(qkv_kernel, dim3(256), dim3(512), 0, stream,
                       seg, gau, Wq, bq, Wk, bk, Wv, bv, Qt, Kt, Vtok, Vswz);
    hipLaunchKernelGGL(attn_kernel, dim3(512), dim3(512), 0, stream,
                       Qt, Kt, Vtok, Vswz, ln1w, ln1b, ln2w, ln2b,
                       W1, b1, W2, b2, outp);
}